// Round 11
// baseline (63.555 us; speedup 1.0000x reference)
//
#include <hip/hip_runtime.h>

// ---------------- constants ----------------
constexpr int kH = 192, kW = 256, kHW = kH * kW;
constexpr int kFH = 48, kFW = 64, kFHW = kFH * kFW;
constexpr int kMH = 39, kMW = 51;
constexpr int kL = kMH * kMW;          // 1989
constexpr int kLP = 2048;              // padded q length
constexpr int kHeads = 32;
constexpr float kInitH = 256.0f / 5.0f; // init_h = W/INIT_SCALE
constexpr float kInitW = 192.0f / 5.0f; // init_w = H/INIT_SCALE
constexpr float kL2E = 1.44269504088896340736f;
constexpr float kBias = -16.0f;        // log2-domain bias (cancels in n/den)
// pad q (kL..kLP): K=0 -> e = 2^kBias exactly; V=(-1,-1). Analytic removal:
constexpr float kPadCorr = 59.0f / 65536.0f;   // 59 * 2^-16, exact in fp32

typedef float v2f __attribute__((ext_vector_type(2)));
typedef unsigned long long u64;

// d = a * b + c, with b coming from an SGPR pair (wave-uniform K/V data).
// VOP3P allows exactly one scalar operand; generic lowering would instead
// emit 2x v_mov_b32 per uniform operand (the ~2.5x VALU inflation seen).
__device__ __forceinline__ v2f pk_fma3(v2f a, u64 b_s, v2f c) {
  v2f d;
  asm("v_pk_fma_f32 %0, %1, %2, %3" : "=v"(d) : "v"(a), "s"(b_s), "v"(c));
  return d;
}

// raw hardware exp2: args in [-40, 0] — no denormal/range fixup needed.
__device__ __forceinline__ float fast_exp2(float x) {
#if __has_builtin(__builtin_amdgcn_exp2f)
  return __builtin_amdgcn_exp2f(x);
#else
  float r;
  asm("v_exp_f32 %0, %1\n\ts_nop 1" : "=v"(r) : "v"(x));
  return r;
#endif
}

struct HeadParams {
  int use;
  int ntop_c, nleft_c, nh_c, nw_c, dy1_c, dx1_c;   // ntop = new_top = max(top,0)
  int ntop_p, nleft_p, nh_p, nw_p, dy1_p, dx1_p;
  float h_c, w_c, h_p, w_p;
};

__device__ __forceinline__ float sigf(float x) { return 1.0f / (1.0f + __expf(-x)); }
__device__ __forceinline__ float stepH(int j) { return (float)(2 * abs(j - 19) + 1); }
__device__ __forceinline__ float stepW(int j) { return (float)(2 * abs(j - 25) + 1); }

__device__ void headParams(int i, const int* clm, const int* plm, const float* sp, HeadParams& h) {
  int ccx = clm[2 * i], ccy = clm[2 * i + 1];
  int pcx = plm[2 * i], pcy = plm[2 * i + 1];
  h.use = !(((ccx == 0) && (ccy == 0)) || ((pcx == 0) && (pcy == 0)));
  {
    int top = ccy - (kMH + 1) / 2, bottom = ccy + kMH / 2;
    int left = ccx - (kMW + 1) / 2, right = ccx + kMW / 2;
    int dy1 = max(-top, 0), dy2 = max(bottom - kH, 0);
    int dx1 = max(-left, 0), dx2 = max(right - kW, 0);
    h.ntop_c = top + dy1; h.nleft_c = left + dx1; h.dy1_c = dy1; h.dx1_c = dx1;
    h.nh_c = max(kMH - dy1 - dy2, 0); h.nw_c = max(kMW - dx1 - dx2, 0);
  }
  {
    int top = pcy - (kMH + 1) / 2, bottom = pcy + kMH / 2;
    int left = pcx - (kMW + 1) / 2, right = pcx + kMW / 2;
    int dy1 = max(-top, 0), dy2 = max(bottom - kH, 0);
    int dx1 = max(-left, 0), dx2 = max(right - kW, 0);
    h.ntop_p = top + dy1; h.nleft_p = left + dx1; h.dy1_p = dy1; h.dx1_p = dx1;
    h.nh_p = max(kMH - dy1 - dy2, 0); h.nw_p = max(kMW - dx1 - dx2, 0);
  }
  float adj_cw = sp[4 * i + 0], adj_ch = sp[4 * i + 1];
  float adj_pw = sp[4 * i + 2], adj_ph = sp[4 * i + 3];
  h.h_c = kInitH * sigf(adj_ch);
  h.w_c = kInitW * sigf(adj_cw);
  h.h_p = kInitH * sigf(adj_ph);
  h.w_p = kInitW * sigf(adj_pw);
}

// on-the-fly 64->4 prelu+1x1 conv at one quarter-res pixel, scaled by s
__device__ __forceinline__ float4 conv4(const float* __restrict__ f, const float* __restrict__ w,
                                        const float* __restrict__ b, float a, int fpix, float s) {
  float acc0 = 0.f, acc1 = 0.f, acc2 = 0.f, acc3 = 0.f;
#pragma unroll 8
  for (int c = 0; c < 64; ++c) {
    float x = f[c * kFHW + fpix];
    float pr = fmaxf(x, 0.f) + a * fminf(x, 0.f);
    acc0 = fmaf(pr, w[c], acc0);
    acc1 = fmaf(pr, w[64 + c], acc1);
    acc2 = fmaf(pr, w[128 + c], acc2);
    acc3 = fmaf(pr, w[192 + c], acc3);
  }
  return make_float4((acc0 + b[0]) * s, (acc1 + b[1]) * s, (acc2 + b[2]) * s, (acc3 + b[3]) * s);
}

// -------- fused: head params (block-level) + on-the-fly conv + patch materialization --------
// K planes: Kpl[c][i][q] c=0..3, plane stride 32*2048. V planes: Vpl[d][i][q] d=0..1.
__global__ void k_patch(const float* __restrict__ fc, const float* __restrict__ fp,
                        const float* __restrict__ w1, const float* __restrict__ b1, const float* __restrict__ a1,
                        const float* __restrict__ w2, const float* __restrict__ b2, const float* __restrict__ a2,
                        const float* __restrict__ loc,
                        const float* __restrict__ sp, const int* __restrict__ clm, const int* __restrict__ plm,
                        float* __restrict__ Kpl, float* __restrict__ Vpl, float4* __restrict__ Pall,
                        int* __restrict__ hpws) {
  __shared__ int shp[20];
  int i = blockIdx.y;
  if (threadIdx.x == 0) {
    HeadParams h; headParams(i, clm, plm, sp, h);
    shp[0] = h.use;
    shp[1] = h.ntop_c; shp[2] = h.nleft_c; shp[3] = h.nh_c; shp[4] = h.nw_c; shp[5] = h.dy1_c; shp[6] = h.dx1_c;
    shp[7] = h.ntop_p; shp[8] = h.nleft_p; shp[9] = h.nh_p; shp[10] = h.nw_p; shp[11] = h.dy1_p; shp[12] = h.dx1_p;
    shp[13] = __float_as_int(h.h_c); shp[14] = __float_as_int(h.w_c);
    shp[15] = __float_as_int(h.h_p); shp[16] = __float_as_int(h.w_p);
    if (blockIdx.x == 0) {       // persist for k_merge_full (read after this kernel completes)
      int* o = hpws + i * 20;
#pragma unroll
      for (int t = 0; t < 17; ++t) o[t] = shp[t];
    }
  }
  __syncthreads();
  int use = shp[0];
  int ntop_c = shp[1], nleft_c = shp[2], nh_c = shp[3], nw_c = shp[4], dy1_c = shp[5], dx1_c = shp[6];
  int ntop_p = shp[7], nleft_p = shp[8], nh_p = shp[9], nw_p = shp[10], dy1_p = shp[11], dx1_p = shp[12];
  float h_c = __int_as_float(shp[13]), w_c = __int_as_float(shp[14]);
  float h_p = __int_as_float(shp[15]), w_p = __int_as_float(shp[16]);

  int q = blockIdx.x * 256 + threadIdx.x;   // q in [0, 2048)
  int qr = q / kMW, qc = q - qr * kMW;
  constexpr int PS = kHeads * kLP;          // plane stride
  int o = i * kLP + q;
  float a1v = a1[0], a2v = a2[0];
  // c-side -> K, V (pad q >= kL: K=0, V=-1, corrected analytically in merge)
  {
    bool val = (q < kL) && use && (qr < nh_c) && (qc < nw_c);
    int row = min(ntop_c + qr, kH - 1);
    int col = min(nleft_c + qc, kW - 1);
    int mr = min(dy1_c + qr, kMH - 1);
    int mc = min(dx1_c + qc, kMW - 1);
    float mv = sigf((h_c - stepH(mr)) * 2.f) * sigf((w_c - stepW(mc)) * 2.f);
    int fpix = (row >> 2) * kFW + (col >> 2);
    float kx = 0.f, ky = 0.f, kz = 0.f, kw = 0.f, vx = -1.f, vy = -1.f;
    if (val) {
      float4 k = conv4(fc, w1, b1, a1v, fpix, mv);
      kx = k.x; ky = k.y; kz = k.z; kw = k.w;
      vx = loc[(2 * i) * kHW + row * kW + col];
      vy = loc[(2 * i + 1) * kHW + row * kW + col];
    }
    Kpl[o] = kx; Kpl[PS + o] = ky; Kpl[2 * PS + o] = kz; Kpl[3 * PS + o] = kw;
    Vpl[o] = vx; Vpl[PS + o] = vy;
  }
  // p-side -> P (scaled by log2e so exp2 needs no extra multiply)
  if (q < kL) {
    bool val = use && (qr < nh_p) && (qc < nw_p);
    int row = min(ntop_p + qr, kH - 1);
    int col = min(nleft_p + qc, kW - 1);
    int mr = min(dy1_p + qr, kMH - 1);
    int mc = min(dx1_p + qc, kMW - 1);
    float mv = sigf((h_p - stepH(mr)) * 2.f) * sigf((w_p - stepW(mc)) * 2.f) * kL2E;
    int fpix = (row >> 2) * kFW + (col >> 2);
    float4 pv = make_float4(0.f, 0.f, 0.f, 0.f);
    if (val) pv = conv4(fp, w2, b2, a2v, fpix, mv);
    Pall[i * kL + q] = pv;
  }
}

// -------- single-pass partial softmax-attention; SGPR-direct v_pk_fma_f32 inner loop --------
template<int QLEN>
__global__ void __launch_bounds__(256) k_attn_t(const float* __restrict__ Kpl, const float* __restrict__ Vpl,
                                                const float4* __restrict__ Pall,
                                                float* __restrict__ pD, float* __restrict__ pX,
                                                float* __restrict__ pY) {
  constexpr int PS = kHeads * kLP;
  int i = blockIdx.z;
  int qsi = blockIdx.y;
  int p = blockIdx.x * 249 + threadIdx.x;
  int pe = min(p, kL - 1);
  const int base = i * kLP + qsi * QLEN;   // 8B-aligned u64 reads (QLEN even)
  const u64* kx = (const u64*)(Kpl + base);
  const u64* ky = (const u64*)(Kpl + PS + base);
  const u64* kz = (const u64*)(Kpl + 2 * PS + base);
  const u64* kw = (const u64*)(Kpl + 3 * PS + base);
  const u64* vx = (const u64*)(Vpl + base);
  const u64* vy = (const u64*)(Vpl + PS + base);
  float4 P = Pall[i * kL + pe];
  v2f PX = {P.x, P.x}, PY = {P.y, P.y}, PZ = {P.z, P.z}, PW = {P.w, P.w};
  const v2f Bv = {kBias, kBias};           // lives in a VGPR pair across the loop
  v2f dA = {0.f, 0.f}, dB = {0.f, 0.f};
  v2f xA = {0.f, 0.f}, xB = {0.f, 0.f};
  v2f yA = {0.f, 0.f}, yB = {0.f, 0.f};
#pragma unroll 8
  for (int t = 0; t < QLEN / 2; t += 2) {  // t indexes q-pairs
    u64 KxA = kx[t], KyA = ky[t], KzA = kz[t], KwA = kw[t];
    u64 KxB = kx[t + 1], KyB = ky[t + 1], KzB = kz[t + 1], KwB = kw[t + 1];
    u64 VxA = vx[t], VyA = vy[t], VxB = vx[t + 1], VyB = vy[t + 1];
    v2f sA = pk_fma3(PW, KwA, Bv);
    sA = pk_fma3(PZ, KzA, sA);
    sA = pk_fma3(PY, KyA, sA);
    sA = pk_fma3(PX, KxA, sA);
    v2f sB = pk_fma3(PW, KwB, Bv);
    sB = pk_fma3(PZ, KzB, sB);
    sB = pk_fma3(PY, KyB, sB);
    sB = pk_fma3(PX, KxB, sB);
    v2f eA = {fast_exp2(sA.x), fast_exp2(sA.y)};
    v2f eB = {fast_exp2(sB.x), fast_exp2(sB.y)};
    dA += eA;
    xA = pk_fma3(eA, VxA, xA);
    yA = pk_fma3(eA, VyA, yA);
    dB += eB;
    xB = pk_fma3(eB, VxB, xB);
    yB = pk_fma3(eB, VyB, yB);
  }
  int o = (i * gridDim.y + qsi) * kLP + pe;
  pD[o] = dA.x + dA.y + dB.x + dB.y;
  pX[o] = xA.x + xA.y + xB.x + xB.y;
  pY[o] = yA.x + yA.y + yB.x + yB.y;
}

// -------- full-image merge: init + partial-merge + inverse-map scatter, all coalesced --------
__global__ void k_merge_full(const float* __restrict__ pD, const float* __restrict__ pX,
                             const float* __restrict__ pY, int QS,
                             const int* __restrict__ hpws, float* __restrict__ out) {
  int i = blockIdx.y;
  int pix = blockIdx.x * 256 + threadIdx.x;   // < kHW
  const int* hp = hpws + i * 20;              // wave-uniform -> scalar loads
  int use = hp[0];
  int ntop_p = hp[7], nleft_p = hp[8], nh_p = hp[9], nw_p = hp[10];
  int r = pix >> 8;          // kW = 256
  int c = pix & 255;
  int pr = r - ntop_p, pc = c - nleft_p;
  bool val = use && ((unsigned)pr < (unsigned)nh_p) && ((unsigned)pc < (unsigned)nw_p);
  float f0 = -1.f, f1 = -1.f, mk = 0.f;
  if (val) {
    int p = pr * kMW + pc;
    float den = -kPadCorr, n0 = kPadCorr, n1 = kPadCorr;  // remove pad-q contribution
    for (int k = 0; k < QS; ++k) {
      int o = (i * QS + k) * kLP + p;
      den += pD[o]; n0 += pX[o]; n1 += pY[o];
    }
    float inv = 1.0f / den;
    f0 = n0 * inv; f1 = n1 * inv; mk = 1.0f;
  }
  out[(2 * i) * kHW + pix]      = f0;
  out[(2 * i + 1) * kHW + pix]  = f1;
  out[64 * kHW + i * kHW + pix] = mk;
}

extern "C" void kernel_launch(void* const* d_in, const int* in_sizes, int n_in,
                              void* d_out, int out_size, void* d_ws, size_t ws_size,
                              hipStream_t stream) {
  (void)in_sizes; (void)n_in; (void)out_size;
  const float* loc = (const float*)d_in[0];
  const float* fc  = (const float*)d_in[1];
  const float* fp  = (const float*)d_in[2];
  const float* sp  = (const float*)d_in[3];
  const int* clm   = (const int*)d_in[6];
  const int* plm   = (const int*)d_in[7];
  const float* w1  = (const float*)d_in[8];
  const float* b1  = (const float*)d_in[9];
  const float* a1  = (const float*)d_in[10];
  const float* w2  = (const float*)d_in[11];
  const float* b2  = (const float*)d_in[12];
  const float* a2  = (const float*)d_in[13];
  float* out = (float*)d_out;
  char* ws = (char*)d_ws;

  // workspace layout (16B aligned)
  int*    hpws = (int*)(ws);                   // 32*20*4 = 2560 B (pad to 4096)
  float*  Kpl  = (float*)(ws + 4096);          // 4*32*2048*4 = 1,048,576 B
  float*  Vpl  = (float*)(ws + 1052672);       // 2*32*2048*4 =   524,288 B
  float4* Pall = (float4*)(ws + 1576960);      // 32*1989*16  = 1,018,368 B
  size_t base = 2595328;
  size_t perQS = (size_t)3 * kHeads * kLP * 4; // 786,432 B per q-slice (3 planes)
  int QS = 1;
  if (ws_size >= base + 16 * perQS) QS = 16;
  else if (ws_size >= base + 8 * perQS) QS = 8;
  else if (ws_size >= base + 4 * perQS) QS = 4;
  else if (ws_size >= base + 2 * perQS) QS = 2;
  float* pD = (float*)(ws + base);
  float* pX = pD + (size_t)QS * kHeads * kLP;
  float* pY = pX + (size_t)QS * kHeads * kLP;

  k_patch<<<dim3(kLP / 256, kHeads), 256, 0, stream>>>(fc, fp, w1, b1, a1, w2, b2, a2,
                                                       loc, sp, clm, plm, Kpl, Vpl, Pall, hpws);
  dim3 ag(8, QS, kHeads);
  switch (QS) {
    case 16: k_attn_t<128><<<ag, 256, 0, stream>>>(Kpl, Vpl, Pall, pD, pX, pY); break;
    case 8:  k_attn_t<256><<<ag, 256, 0, stream>>>(Kpl, Vpl, Pall, pD, pX, pY); break;
    case 4:  k_attn_t<512><<<ag, 256, 0, stream>>>(Kpl, Vpl, Pall, pD, pX, pY); break;
    case 2:  k_attn_t<1024><<<ag, 256, 0, stream>>>(Kpl, Vpl, Pall, pD, pX, pY); break;
    default: k_attn_t<2048><<<ag, 256, 0, stream>>>(Kpl, Vpl, Pall, pD, pX, pY); break;
  }
  k_merge_full<<<dim3(kHW / 256, kHeads), 256, 0, stream>>>(pD, pX, pY, QS, hpws, out);
}

// Round 12
// 55.781 us; speedup vs baseline: 1.1394x; 1.1394x over previous
//
#include <hip/hip_runtime.h>

// ---------------- constants ----------------
constexpr int kH = 192, kW = 256, kHW = kH * kW;
constexpr int kFH = 48, kFW = 64, kFHW = kFH * kFW;
constexpr int kMH = 39, kMW = 51;
constexpr int kL = kMH * kMW;          // 1989
constexpr int kLP = 2048;              // padded q length
constexpr int kHeads = 32;
constexpr float kInitH = 256.0f / 5.0f; // init_h = W/INIT_SCALE
constexpr float kInitW = 192.0f / 5.0f; // init_w = H/INIT_SCALE
constexpr float kL2E = 1.44269504088896340736f;
constexpr float kBias = -16.0f;        // log2-domain bias (cancels in n/den)
// pad q (kL..kLP): K=0 -> e = 2^kBias exactly; V=(-1,-1). Analytic removal:
constexpr float kPadCorr = 59.0f / 65536.0f;   // 59 * 2^-16, exact in fp32

typedef float v2f __attribute__((ext_vector_type(2)));
__device__ __forceinline__ v2f pkfma(v2f a, v2f b, v2f c) {
  return __builtin_elementwise_fma(a, b, c);
}

// raw hardware exp2: args in [-40, 0] — no denormal/range fixup needed.
__device__ __forceinline__ float fast_exp2(float x) {
#if __has_builtin(__builtin_amdgcn_exp2f)
  return __builtin_amdgcn_exp2f(x);
#else
  float r;
  asm("v_exp_f32 %0, %1\n\ts_nop 1" : "=v"(r) : "v"(x));
  return r;
#endif
}

struct HeadParams {
  int use;
  int ntop_c, nleft_c, nh_c, nw_c, dy1_c, dx1_c;   // ntop = new_top = max(top,0)
  int ntop_p, nleft_p, nh_p, nw_p, dy1_p, dx1_p;
  float h_c, w_c, h_p, w_p;
};

__device__ __forceinline__ float sigf(float x) { return 1.0f / (1.0f + __expf(-x)); }
__device__ __forceinline__ float stepH(int j) { return (float)(2 * abs(j - 19) + 1); }
__device__ __forceinline__ float stepW(int j) { return (float)(2 * abs(j - 25) + 1); }

__device__ void headParams(int i, const int* clm, const int* plm, const float* sp, HeadParams& h) {
  int ccx = clm[2 * i], ccy = clm[2 * i + 1];
  int pcx = plm[2 * i], pcy = plm[2 * i + 1];
  h.use = !(((ccx == 0) && (ccy == 0)) || ((pcx == 0) && (pcy == 0)));
  {
    int top = ccy - (kMH + 1) / 2, bottom = ccy + kMH / 2;
    int left = ccx - (kMW + 1) / 2, right = ccx + kMW / 2;
    int dy1 = max(-top, 0), dy2 = max(bottom - kH, 0);
    int dx1 = max(-left, 0), dx2 = max(right - kW, 0);
    h.ntop_c = top + dy1; h.nleft_c = left + dx1; h.dy1_c = dy1; h.dx1_c = dx1;
    h.nh_c = max(kMH - dy1 - dy2, 0); h.nw_c = max(kMW - dx1 - dx2, 0);
  }
  {
    int top = pcy - (kMH + 1) / 2, bottom = pcy + kMH / 2;
    int left = pcx - (kMW + 1) / 2, right = pcx + kMW / 2;
    int dy1 = max(-top, 0), dy2 = max(bottom - kH, 0);
    int dx1 = max(-left, 0), dx2 = max(right - kW, 0);
    h.ntop_p = top + dy1; h.nleft_p = left + dx1; h.dy1_p = dy1; h.dx1_p = dx1;
    h.nh_p = max(kMH - dy1 - dy2, 0); h.nw_p = max(kMW - dx1 - dx2, 0);
  }
  float adj_cw = sp[4 * i + 0], adj_ch = sp[4 * i + 1];
  float adj_pw = sp[4 * i + 2], adj_ph = sp[4 * i + 3];
  h.h_c = kInitH * sigf(adj_ch);
  h.w_c = kInitW * sigf(adj_cw);
  h.h_p = kInitH * sigf(adj_ph);
  h.w_p = kInitW * sigf(adj_pw);
}

// on-the-fly 64->4 prelu+1x1 conv at one quarter-res pixel, scaled by s
__device__ __forceinline__ float4 conv4(const float* __restrict__ f, const float* __restrict__ w,
                                        const float* __restrict__ b, float a, int fpix, float s) {
  float acc0 = 0.f, acc1 = 0.f, acc2 = 0.f, acc3 = 0.f;
#pragma unroll 8
  for (int c = 0; c < 64; ++c) {
    float x = f[c * kFHW + fpix];
    float pr = fmaxf(x, 0.f) + a * fminf(x, 0.f);
    acc0 = fmaf(pr, w[c], acc0);
    acc1 = fmaf(pr, w[64 + c], acc1);
    acc2 = fmaf(pr, w[128 + c], acc2);
    acc3 = fmaf(pr, w[192 + c], acc3);
  }
  return make_float4((acc0 + b[0]) * s, (acc1 + b[1]) * s, (acc2 + b[2]) * s, (acc3 + b[3]) * s);
}

// -------- fused: head params (block-level) + on-the-fly conv + patch materialization --------
// K planes: Kpl[c][i][q] c=0..3, plane stride 32*2048. V planes: Vpl[d][i][q] d=0..1.
__global__ void k_patch(const float* __restrict__ fc, const float* __restrict__ fp,
                        const float* __restrict__ w1, const float* __restrict__ b1, const float* __restrict__ a1,
                        const float* __restrict__ w2, const float* __restrict__ b2, const float* __restrict__ a2,
                        const float* __restrict__ loc,
                        const float* __restrict__ sp, const int* __restrict__ clm, const int* __restrict__ plm,
                        float* __restrict__ Kpl, float* __restrict__ Vpl, float4* __restrict__ Pall,
                        int* __restrict__ hpws) {
  __shared__ int shp[20];
  int i = blockIdx.y;
  if (threadIdx.x == 0) {
    HeadParams h; headParams(i, clm, plm, sp, h);
    shp[0] = h.use;
    shp[1] = h.ntop_c; shp[2] = h.nleft_c; shp[3] = h.nh_c; shp[4] = h.nw_c; shp[5] = h.dy1_c; shp[6] = h.dx1_c;
    shp[7] = h.ntop_p; shp[8] = h.nleft_p; shp[9] = h.nh_p; shp[10] = h.nw_p; shp[11] = h.dy1_p; shp[12] = h.dx1_p;
    shp[13] = __float_as_int(h.h_c); shp[14] = __float_as_int(h.w_c);
    shp[15] = __float_as_int(h.h_p); shp[16] = __float_as_int(h.w_p);
    if (blockIdx.x == 0) {       // persist for k_merge_full (read after this kernel completes)
      int* o = hpws + i * 20;
#pragma unroll
      for (int t = 0; t < 17; ++t) o[t] = shp[t];
    }
  }
  __syncthreads();
  int use = shp[0];
  int ntop_c = shp[1], nleft_c = shp[2], nh_c = shp[3], nw_c = shp[4], dy1_c = shp[5], dx1_c = shp[6];
  int ntop_p = shp[7], nleft_p = shp[8], nh_p = shp[9], nw_p = shp[10], dy1_p = shp[11], dx1_p = shp[12];
  float h_c = __int_as_float(shp[13]), w_c = __int_as_float(shp[14]);
  float h_p = __int_as_float(shp[15]), w_p = __int_as_float(shp[16]);

  int q = blockIdx.x * 256 + threadIdx.x;   // q in [0, 2048)
  int qr = q / kMW, qc = q - qr * kMW;
  constexpr int PS = kHeads * kLP;          // plane stride
  int o = i * kLP + q;
  float a1v = a1[0], a2v = a2[0];
  // c-side -> K, V (pad q >= kL: K=0, V=-1, corrected analytically in merge)
  {
    bool val = (q < kL) && use && (qr < nh_c) && (qc < nw_c);
    int row = min(ntop_c + qr, kH - 1);
    int col = min(nleft_c + qc, kW - 1);
    int mr = min(dy1_c + qr, kMH - 1);
    int mc = min(dx1_c + qc, kMW - 1);
    float mv = sigf((h_c - stepH(mr)) * 2.f) * sigf((w_c - stepW(mc)) * 2.f);
    int fpix = (row >> 2) * kFW + (col >> 2);
    float kx = 0.f, ky = 0.f, kz = 0.f, kw = 0.f, vx = -1.f, vy = -1.f;
    if (val) {
      float4 k = conv4(fc, w1, b1, a1v, fpix, mv);
      kx = k.x; ky = k.y; kz = k.z; kw = k.w;
      vx = loc[(2 * i) * kHW + row * kW + col];
      vy = loc[(2 * i + 1) * kHW + row * kW + col];
    }
    Kpl[o] = kx; Kpl[PS + o] = ky; Kpl[2 * PS + o] = kz; Kpl[3 * PS + o] = kw;
    Vpl[o] = vx; Vpl[PS + o] = vy;
  }
  // p-side -> P (scaled by log2e so exp2 needs no extra multiply)
  if (q < kL) {
    bool val = use && (qr < nh_p) && (qc < nw_p);
    int row = min(ntop_p + qr, kH - 1);
    int col = min(nleft_p + qc, kW - 1);
    int mr = min(dy1_p + qr, kMH - 1);
    int mc = min(dx1_p + qc, kMW - 1);
    float mv = sigf((h_p - stepH(mr)) * 2.f) * sigf((w_p - stepW(mc)) * 2.f) * kL2E;
    int fpix = (row >> 2) * kFW + (col >> 2);
    float4 pv = make_float4(0.f, 0.f, 0.f, 0.f);
    if (val) pv = conv4(fp, w2, b2, a2v, fpix, mv);
    Pall[i * kL + q] = pv;
  }
}

// -------- single-pass partial softmax-attention, packed fp32, static trip count --------
// (R10 proven config: QLEN=128, v2f planar loads, unroll 8, 4 chains; float4 partial store)
template<int QLEN>
__global__ void __launch_bounds__(256) k_attn_t(const float* __restrict__ Kpl, const float* __restrict__ Vpl,
                                                const float4* __restrict__ Pall,
                                                float4* __restrict__ pPart) {
  constexpr int PS = kHeads * kLP;
  int i = blockIdx.z;
  int qsi = blockIdx.y;
  int p = blockIdx.x * 249 + threadIdx.x;
  int pe = min(p, kL - 1);
  const int base = i * kLP + qsi * QLEN;
  const float* kx = Kpl + base;
  const float* ky = Kpl + PS + base;
  const float* kz = Kpl + 2 * PS + base;
  const float* kw = Kpl + 3 * PS + base;
  const float* vx = Vpl + base;
  const float* vy = Vpl + PS + base;
  float4 P = Pall[i * kL + pe];
  v2f PX = {P.x, P.x}, PY = {P.y, P.y}, PZ = {P.z, P.z}, PW = {P.w, P.w};
  const v2f B = {kBias, kBias};
  v2f dA = {0.f, 0.f}, dB = {0.f, 0.f};
  v2f xA = {0.f, 0.f}, xB = {0.f, 0.f};
  v2f yA = {0.f, 0.f}, yB = {0.f, 0.f};
#pragma unroll 8
  for (int t = 0; t < QLEN; t += 4) {
    // pair A: q = t, t+1
    v2f sA = pkfma(PW, *(const v2f*)(kw + t), B);
    sA = pkfma(PZ, *(const v2f*)(kz + t), sA);
    sA = pkfma(PY, *(const v2f*)(ky + t), sA);
    sA = pkfma(PX, *(const v2f*)(kx + t), sA);
    // pair B: q = t+2, t+3
    v2f sB = pkfma(PW, *(const v2f*)(kw + t + 2), B);
    sB = pkfma(PZ, *(const v2f*)(kz + t + 2), sB);
    sB = pkfma(PY, *(const v2f*)(ky + t + 2), sB);
    sB = pkfma(PX, *(const v2f*)(kx + t + 2), sB);
    v2f eA = {fast_exp2(sA.x), fast_exp2(sA.y)};
    v2f eB = {fast_exp2(sB.x), fast_exp2(sB.y)};
    dA += eA;
    xA = pkfma(eA, *(const v2f*)(vx + t), xA);
    yA = pkfma(eA, *(const v2f*)(vy + t), yA);
    dB += eB;
    xB = pkfma(eB, *(const v2f*)(vx + t + 2), xB);
    yB = pkfma(eB, *(const v2f*)(vy + t + 2), yB);
  }
  pPart[(i * gridDim.y + qsi) * kLP + pe] =
      make_float4(dA.x + dA.y + dB.x + dB.y,
                  xA.x + xA.y + xB.x + xB.y,
                  yA.x + yA.y + yB.x + yB.y, 0.f);
}

// -------- full-image merge: init + partial-merge + inverse-map scatter, all coalesced --------
__global__ void k_merge_full(const float4* __restrict__ pPart, int QS,
                             const int* __restrict__ hpws, float* __restrict__ out) {
  int i = blockIdx.y;
  int pix = blockIdx.x * 256 + threadIdx.x;   // < kHW
  const int* hp = hpws + i * 20;              // wave-uniform -> scalar loads
  int use = hp[0];
  int ntop_p = hp[7], nleft_p = hp[8], nh_p = hp[9], nw_p = hp[10];
  int r = pix >> 8;          // kW = 256
  int c = pix & 255;
  int pr = r - ntop_p, pc = c - nleft_p;
  bool val = use && ((unsigned)pr < (unsigned)nh_p) && ((unsigned)pc < (unsigned)nw_p);
  float f0 = -1.f, f1 = -1.f, mk = 0.f;
  if (val) {
    int p = pr * kMW + pc;
    float den = -kPadCorr, n0 = kPadCorr, n1 = kPadCorr;  // remove pad-q contribution
    for (int k = 0; k < QS; ++k) {
      float4 t = pPart[(i * QS + k) * kLP + p];
      den += t.x; n0 += t.y; n1 += t.z;
    }
    float inv = 1.0f / den;
    f0 = n0 * inv; f1 = n1 * inv; mk = 1.0f;
  }
  out[(2 * i) * kHW + pix]      = f0;
  out[(2 * i + 1) * kHW + pix]  = f1;
  out[64 * kHW + i * kHW + pix] = mk;
}

extern "C" void kernel_launch(void* const* d_in, const int* in_sizes, int n_in,
                              void* d_out, int out_size, void* d_ws, size_t ws_size,
                              hipStream_t stream) {
  (void)in_sizes; (void)n_in; (void)out_size;
  const float* loc = (const float*)d_in[0];
  const float* fc  = (const float*)d_in[1];
  const float* fp  = (const float*)d_in[2];
  const float* sp  = (const float*)d_in[3];
  const int* clm   = (const int*)d_in[6];
  const int* plm   = (const int*)d_in[7];
  const float* w1  = (const float*)d_in[8];
  const float* b1  = (const float*)d_in[9];
  const float* a1  = (const float*)d_in[10];
  const float* w2  = (const float*)d_in[11];
  const float* b2  = (const float*)d_in[12];
  const float* a2  = (const float*)d_in[13];
  float* out = (float*)d_out;
  char* ws = (char*)d_ws;

  // workspace layout (16B aligned)
  int*    hpws = (int*)(ws);                   // 32*20*4 = 2560 B (pad to 4096)
  float*  Kpl  = (float*)(ws + 4096);          // 4*32*2048*4 = 1,048,576 B
  float*  Vpl  = (float*)(ws + 1052672);       // 2*32*2048*4 =   524,288 B
  float4* Pall = (float4*)(ws + 1576960);      // 32*1989*16  = 1,018,368 B
  size_t base = 2595328;
  size_t perQS = (size_t)kHeads * kLP * 16;    // 1 MiB per q-slice (float4 partials)
  int QS = 1;
  if (ws_size >= base + 16 * perQS) QS = 16;
  else if (ws_size >= base + 8 * perQS) QS = 8;
  else if (ws_size >= base + 4 * perQS) QS = 4;
  else if (ws_size >= base + 2 * perQS) QS = 2;
  float4* pPart = (float4*)(ws + base);

  k_patch<<<dim3(kLP / 256, kHeads), 256, 0, stream>>>(fc, fp, w1, b1, a1, w2, b2, a2,
                                                       loc, sp, clm, plm, Kpl, Vpl, Pall, hpws);
  dim3 ag(8, QS, kHeads);
  switch (QS) {
    case 16: k_attn_t<128><<<ag, 256, 0, stream>>>(Kpl, Vpl, Pall, pPart); break;
    case 8:  k_attn_t<256><<<ag, 256, 0, stream>>>(Kpl, Vpl, Pall, pPart); break;
    case 4:  k_attn_t<512><<<ag, 256, 0, stream>>>(Kpl, Vpl, Pall, pPart); break;
    case 2:  k_attn_t<1024><<<ag, 256, 0, stream>>>(Kpl, Vpl, Pall, pPart); break;
    default: k_attn_t<2048><<<ag, 256, 0, stream>>>(Kpl, Vpl, Pall, pPart); break;
  }
  k_merge_full<<<dim3(kHW / 256, kHeads), 256, 0, stream>>>(pPart, QS, hpws, out);
}